// Round 2
// baseline (2092.211 us; speedup 1.0000x reference)
//
#include <hip/hip_runtime.h>
#include <hip/hip_bf16.h>

#define NN 100000
#define NE 1000000
#define DD 128
#define RR 8

typedef short bf16x8 __attribute__((ext_vector_type(8)));
typedef float f32x4 __attribute__((ext_vector_type(4)));

__device__ __forceinline__ unsigned short f2bf(float f) {
    union { float f; unsigned int u; } c; c.f = f;
    unsigned int u = c.u;
    u += 0x7fffu + ((u >> 16) & 1u);   // round-to-nearest-even
    return (unsigned short)(u >> 16);
}

__device__ __forceinline__ float bf2f(unsigned short s) {
    union { unsigned int u; float f; } c; c.u = ((unsigned int)s) << 16;
    return c.f;
}

// fp32 -> bf16 (optionally relu first), 4 elems/thread
__global__ __launch_bounds__(256) void cvt_x_k(const float* __restrict__ in,
                                               unsigned short* __restrict__ out,
                                               int n4, int relu) {
    int i = blockIdx.x * 256 + threadIdx.x;
    if (i >= n4) return;
    float4 v = reinterpret_cast<const float4*>(in)[i];
    if (relu) {
        v.x = fmaxf(v.x, 0.f); v.y = fmaxf(v.y, 0.f);
        v.z = fmaxf(v.z, 0.f); v.w = fmaxf(v.w, 0.f);
    }
    ushort4 o;
    o.x = f2bf(v.x); o.y = f2bf(v.y); o.z = f2bf(v.z); o.w = f2bf(v.w);
    reinterpret_cast<ushort4*>(out)[i] = o;
}

// W [r][d][e] fp32 -> Wt [m][e][d] bf16 (m=0..7 relations, m=8 root), both layers
__global__ __launch_bounds__(256) void cvt_w_k(const float* __restrict__ W1,
                                               const float* __restrict__ r1,
                                               const float* __restrict__ W2,
                                               const float* __restrict__ r2,
                                               unsigned short* __restrict__ wt1,
                                               unsigned short* __restrict__ wt2) {
    int idx = blockIdx.x * 256 + threadIdx.x;       // 0 .. 2*9*128*128-1
    int l   = idx / (9 * DD * DD);
    int rem = idx % (9 * DD * DD);
    int m   = rem / (DD * DD);
    int ed  = rem % (DD * DD);
    int e = ed / DD, d = ed % DD;
    const float* srcm = (l == 0) ? (m < 8 ? W1 + (size_t)m * DD * DD : r1)
                                 : (m < 8 ? W2 + (size_t)m * DD * DD : r2);
    unsigned short* o = (l == 0) ? wt1 : wt2;
    o[rem] = f2bf(srcm[(size_t)d * DD + e]);        // transpose: Wt[e][d] = W[d][e]
}

__global__ __launch_bounds__(256) void deg_k(const int* __restrict__ dst,
                                             const int* __restrict__ et,
                                             unsigned int* __restrict__ deg) {
    int e = blockIdx.x * 256 + threadIdx.x;
    if (e >= NE) return;
    atomicAdd(&deg[(size_t)et[e] * NN + dst[e]], 1u);
}

// One block = 128 nodes; wave w owns 32 nodes. For m in [m0, m0+mcnt):
//   D'[outcol][node] = Wt_frag (A) x x_frag (B)
// m<8: bf16 h chunk store at slot (m-m0); m==8: fp32 root+bias store to acc.
__global__ __launch_bounds__(256) void gemm_k(const unsigned short* __restrict__ xb,
                                              const unsigned short* __restrict__ wt,
                                              const float* __restrict__ bias,
                                              unsigned short* __restrict__ h,
                                              float* __restrict__ acc,
                                              int m0, int mcnt) {
    const int wave = threadIdx.x >> 6;
    const int lane = threadIdx.x & 63;
    const int c16  = lane & 15;
    const int grp  = lane >> 4;
    const int nodeBase = blockIdx.x * 128 + wave * 32;

    // B fragments: x rows, held for all matrices of this chunk
    bf16x8 bfr[2][4];
#pragma unroll
    for (int nt = 0; nt < 2; ++nt) {
        int node = nodeBase + nt * 16 + c16;
        if (node > NN - 1) node = NN - 1;
        const unsigned short* xrow = xb + (size_t)node * DD;
#pragma unroll
        for (int kk = 0; kk < 4; ++kk)
            bfr[nt][kk] = *reinterpret_cast<const bf16x8*>(xrow + kk * 32 + grp * 8);
    }

    for (int mi = 0; mi < mcnt; ++mi) {
        const int m = m0 + mi;
        f32x4 accf[8][2];
#pragma unroll
        for (int oc = 0; oc < 8; ++oc) {
            accf[oc][0] = f32x4{0.f, 0.f, 0.f, 0.f};
            accf[oc][1] = f32x4{0.f, 0.f, 0.f, 0.f};
        }
        const unsigned short* wm = wt + (size_t)m * DD * DD;
#pragma unroll
        for (int oc = 0; oc < 8; ++oc) {
            bf16x8 a[4];
            const unsigned short* wrow = wm + (size_t)(oc * 16 + c16) * DD;
#pragma unroll
            for (int kk = 0; kk < 4; ++kk)
                a[kk] = *reinterpret_cast<const bf16x8*>(wrow + kk * 32 + grp * 8);
#pragma unroll
            for (int kk = 0; kk < 4; ++kk) {
                accf[oc][0] = __builtin_amdgcn_mfma_f32_16x16x32_bf16(a[kk], bfr[0][kk], accf[oc][0], 0, 0, 0);
                accf[oc][1] = __builtin_amdgcn_mfma_f32_16x16x32_bf16(a[kk], bfr[1][kk], accf[oc][1], 0, 0, 0);
            }
        }
        if (m < 8) {
#pragma unroll
            for (int oc = 0; oc < 8; ++oc) {
#pragma unroll
                for (int nt = 0; nt < 2; ++nt) {
                    int node = nodeBase + nt * 16 + c16;
                    if (node >= NN) continue;
                    union { unsigned short s[4]; uint2 v; } pk;
#pragma unroll
                    for (int i = 0; i < 4; ++i) pk.s[i] = f2bf(accf[oc][nt][i]);
                    *reinterpret_cast<uint2*>(h + ((size_t)mi * NN + node) * DD + oc * 16 + grp * 4) = pk.v;
                }
            }
        } else {
#pragma unroll
            for (int oc = 0; oc < 8; ++oc) {
                const float4 bv = *reinterpret_cast<const float4*>(bias + oc * 16 + grp * 4);
#pragma unroll
                for (int nt = 0; nt < 2; ++nt) {
                    int node = nodeBase + nt * 16 + c16;
                    if (node >= NN) continue;
                    float4 o;
                    o.x = accf[oc][nt][0] + bv.x;
                    o.y = accf[oc][nt][1] + bv.y;
                    o.z = accf[oc][nt][2] + bv.z;
                    o.w = accf[oc][nt][3] + bv.w;
                    *reinterpret_cast<float4*>(acc + (size_t)node * DD + oc * 16 + grp * 4) = o;
                }
            }
        }
    }
}

// One wave per edge with etype in [r0, r0+rcnt): gather h chunk (bf16),
// scale by 1/deg(etype,dst), atomicAdd fp32 into acc[dst]
__global__ __launch_bounds__(256) void scatter_k(const int* __restrict__ src,
                                                 const int* __restrict__ dst,
                                                 const int* __restrict__ et,
                                                 const unsigned int* __restrict__ deg,
                                                 const unsigned short* __restrict__ h,
                                                 float* __restrict__ acc,
                                                 int r0, int rcnt) {
    int e = (int)((blockIdx.x * 256 + threadIdx.x) >> 6);
    if (e >= NE) return;
    int r = et[e];
    unsigned int ri = (unsigned int)(r - r0);
    if (ri >= (unsigned int)rcnt) return;
    int lane = threadIdx.x & 63;
    int s = src[e], d0 = dst[e];
    float sc = 1.0f / (float)deg[(size_t)r * NN + d0];
    unsigned int hv = *reinterpret_cast<const unsigned int*>(
        h + ((size_t)ri * NN + s) * DD + lane * 2);
    float f0 = bf2f((unsigned short)(hv & 0xffffu));
    float f1 = bf2f((unsigned short)(hv >> 16));
    float* ap = acc + (size_t)d0 * DD + lane * 2;
    atomicAdd(ap,     f0 * sc);
    atomicAdd(ap + 1, f1 * sc);
}

__global__ __launch_bounds__(256) void relu_ip_k(float* __restrict__ p, int n4) {
    int i = blockIdx.x * 256 + threadIdx.x;
    if (i >= n4) return;
    float4 v = reinterpret_cast<float4*>(p)[i];
    v.x = fmaxf(v.x, 0.f); v.y = fmaxf(v.y, 0.f);
    v.z = fmaxf(v.z, 0.f); v.w = fmaxf(v.w, 0.f);
    reinterpret_cast<float4*>(p)[i] = v;
}

extern "C" void kernel_launch(void* const* d_in, const int* in_sizes, int n_in,
                              void* d_out, int out_size, void* d_ws, size_t ws_size,
                              hipStream_t stream) {
    const float* x  = (const float*)d_in[0];
    const int*   ei = (const int*)d_in[1];
    const int*   et = (const int*)d_in[2];
    const float* W1 = (const float*)d_in[3];
    const float* r1 = (const float*)d_in[4];
    const float* b1 = (const float*)d_in[5];
    const float* W2 = (const float*)d_in[6];
    const float* r2 = (const float*)d_in[7];
    const float* b2 = (const float*)d_in[8];
    float* out = (float*)d_out;

    // workspace layout (adaptive): fixed 29.4 MB + C * 25.6 MB h-chunk
    char* ws = (char*)d_ws;
    unsigned short* xbuf = (unsigned short*)ws;                 // NN*DD bf16 = 25.6 MB
    unsigned short* wt1  = xbuf + (size_t)NN * DD;              // 288 KB
    unsigned short* wt2  = wt1 + 9 * DD * DD;                   // 288 KB
    unsigned int*   deg  = (unsigned int*)(wt2 + 9 * DD * DD);  // 3.2 MB
    unsigned short* h    = (unsigned short*)(deg + (size_t)RR * NN);
    const size_t fixedBytes = (size_t)((char*)h - ws);          // 29,389,824
    const size_t chunkBytes = (size_t)NN * DD * 2;              // 25,600,000
    if (ws_size < fixedBytes + chunkBytes) return;              // can't run at all
    size_t hcap = (ws_size - fixedBytes) / chunkBytes;
    const int C = hcap >= 8 ? 8 : (int)hcap;                    // relations per chunk

    const int* srcv = ei;
    const int* dstv = ei + NE;
    const int gemmGrid = (NN + 127) / 128;
    const int cvtGrid  = (NN * DD / 4 + 255) / 256;

    hipMemsetAsync(deg, 0, sizeof(unsigned int) * (size_t)RR * NN, stream);
    cvt_x_k<<<cvtGrid, 256, 0, stream>>>(x, xbuf, NN * DD / 4, 0);
    cvt_w_k<<<(2 * 9 * DD * DD) / 256, 256, 0, stream>>>(W1, r1, W2, r2, wt1, wt2);
    deg_k<<<(NE + 255) / 256, 256, 0, stream>>>(dstv, et, deg);

    // ---- layer 1 (acc = d_out, fully overwritten by root gemm) ----
    gemm_k<<<gemmGrid, 256, 0, stream>>>(xbuf, wt1, b1, h, out, 8, 1);   // root + bias
    for (int r0 = 0; r0 < RR; r0 += C) {
        int c = (RR - r0) < C ? (RR - r0) : C;
        gemm_k<<<gemmGrid, 256, 0, stream>>>(xbuf, wt1, b1, h, out, r0, c);
        scatter_k<<<NE / 4, 256, 0, stream>>>(srcv, dstv, et, deg, h, out, r0, c);
    }
    cvt_x_k<<<cvtGrid, 256, 0, stream>>>(out, xbuf, NN * DD / 4, 1);     // relu -> bf16

    // ---- layer 2 (acc = d_out) ----
    gemm_k<<<gemmGrid, 256, 0, stream>>>(xbuf, wt2, b2, h, out, 8, 1);   // root + bias
    for (int r0 = 0; r0 < RR; r0 += C) {
        int c = (RR - r0) < C ? (RR - r0) : C;
        gemm_k<<<gemmGrid, 256, 0, stream>>>(xbuf, wt2, b2, h, out, r0, c);
        scatter_k<<<NE / 4, 256, 0, stream>>>(srcv, dstv, et, deg, h, out, r0, c);
    }
    relu_ip_k<<<cvtGrid, 256, 0, stream>>>(out, NN * DD / 4);
}

// Round 3
// 858.902 us; speedup vs baseline: 2.4359x; 2.4359x over previous
//
#include <hip/hip_runtime.h>
#include <hip/hip_bf16.h>

#define NN 100000
#define NE 1000000
#define DD 128
#define RR 8

typedef short bf16x8 __attribute__((ext_vector_type(8)));
typedef float f32x4 __attribute__((ext_vector_type(4)));

__device__ __forceinline__ unsigned short f2bf(float f) {
    union { float f; unsigned int u; } c; c.f = f;
    unsigned int u = c.u;
    u += 0x7fffu + ((u >> 16) & 1u);   // round-to-nearest-even
    return (unsigned short)(u >> 16);
}

__device__ __forceinline__ float bf2f(unsigned short s) {
    union { unsigned int u; float f; } c; c.u = ((unsigned int)s) << 16;
    return c.f;
}

// fp32 -> bf16, 4 elems/thread
__global__ __launch_bounds__(256) void cvt_x_k(const float* __restrict__ in,
                                               unsigned short* __restrict__ out,
                                               int n4) {
    int i = blockIdx.x * 256 + threadIdx.x;
    if (i >= n4) return;
    float4 v = reinterpret_cast<const float4*>(in)[i];
    ushort4 o;
    o.x = f2bf(v.x); o.y = f2bf(v.y); o.z = f2bf(v.z); o.w = f2bf(v.w);
    reinterpret_cast<ushort4*>(out)[i] = o;
}

// W [r][d][e] fp32 -> Wt [m][e][d] bf16 (m=0..7 relations, m=8 root), both layers
__global__ __launch_bounds__(256) void cvt_w_k(const float* __restrict__ W1,
                                               const float* __restrict__ r1,
                                               const float* __restrict__ W2,
                                               const float* __restrict__ r2,
                                               unsigned short* __restrict__ wt1,
                                               unsigned short* __restrict__ wt2) {
    int idx = blockIdx.x * 256 + threadIdx.x;       // 0 .. 2*9*128*128-1
    int l   = idx / (9 * DD * DD);
    int rem = idx % (9 * DD * DD);
    int m   = rem / (DD * DD);
    int ed  = rem % (DD * DD);
    int e = ed / DD, d = ed % DD;
    const float* srcm = (l == 0) ? (m < 8 ? W1 + (size_t)m * DD * DD : r1)
                                 : (m < 8 ? W2 + (size_t)m * DD * DD : r2);
    unsigned short* o = (l == 0) ? wt1 : wt2;
    o[rem] = f2bf(srcm[(size_t)d * DD + e]);        // transpose: Wt[e][d] = W[d][e]
}

// histogram of dst
__global__ __launch_bounds__(256) void hist_k(const int* __restrict__ dst,
                                              unsigned int* __restrict__ degTot) {
    int e = blockIdx.x * 256 + threadIdx.x;
    if (e >= NE) return;
    atomicAdd(&degTot[dst[e]], 1u);
}

// assign segment base offsets (unordered CSR): pos[i] = atomicAdd(counter, degTot[i])
__global__ __launch_bounds__(256) void offsets_k(const unsigned int* __restrict__ degTot,
                                                 unsigned int* __restrict__ counter,
                                                 unsigned int* __restrict__ pos) {
    int i = blockIdx.x * 256 + threadIdx.x;
    if (i >= NN) return;
    pos[i] = atomicAdd(counter, degTot[i]);
}

// scatter packed (src | r<<20) records into per-dst segments
__global__ __launch_bounds__(256) void fill_k(const int* __restrict__ src,
                                              const int* __restrict__ dst,
                                              const int* __restrict__ et,
                                              unsigned int* __restrict__ pos,
                                              unsigned int* __restrict__ sorted) {
    int e = blockIdx.x * 256 + threadIdx.x;
    if (e >= NE) return;
    unsigned int p = atomicAdd(&pos[dst[e]], 1u);
    sorted[p] = (unsigned int)src[e] | ((unsigned int)et[e] << 20);
}

// One block = 128 nodes; wave w owns 32 nodes. For m in [m0, m0+mcnt):
//   D'[outcol][node] = Wt_frag (A) x x_frag (B)
// m<8: bf16 h chunk store at slot (m-m0); m==8: fp32 root+bias store to acc.
__global__ __launch_bounds__(256) void gemm_k(const unsigned short* __restrict__ xb,
                                              const unsigned short* __restrict__ wt,
                                              const float* __restrict__ bias,
                                              unsigned short* __restrict__ h,
                                              float* __restrict__ acc,
                                              int m0, int mcnt) {
    const int wave = threadIdx.x >> 6;
    const int lane = threadIdx.x & 63;
    const int c16  = lane & 15;
    const int grp  = lane >> 4;
    const int nodeBase = blockIdx.x * 128 + wave * 32;

    bf16x8 bfr[2][4];
#pragma unroll
    for (int nt = 0; nt < 2; ++nt) {
        int node = nodeBase + nt * 16 + c16;
        if (node > NN - 1) node = NN - 1;
        const unsigned short* xrow = xb + (size_t)node * DD;
#pragma unroll
        for (int kk = 0; kk < 4; ++kk)
            bfr[nt][kk] = *reinterpret_cast<const bf16x8*>(xrow + kk * 32 + grp * 8);
    }

    for (int mi = 0; mi < mcnt; ++mi) {
        const int m = m0 + mi;
        f32x4 accf[8][2];
#pragma unroll
        for (int oc = 0; oc < 8; ++oc) {
            accf[oc][0] = f32x4{0.f, 0.f, 0.f, 0.f};
            accf[oc][1] = f32x4{0.f, 0.f, 0.f, 0.f};
        }
        const unsigned short* wm = wt + (size_t)m * DD * DD;
#pragma unroll
        for (int oc = 0; oc < 8; ++oc) {
            bf16x8 a[4];
            const unsigned short* wrow = wm + (size_t)(oc * 16 + c16) * DD;
#pragma unroll
            for (int kk = 0; kk < 4; ++kk)
                a[kk] = *reinterpret_cast<const bf16x8*>(wrow + kk * 32 + grp * 8);
#pragma unroll
            for (int kk = 0; kk < 4; ++kk) {
                accf[oc][0] = __builtin_amdgcn_mfma_f32_16x16x32_bf16(a[kk], bfr[0][kk], accf[oc][0], 0, 0, 0);
                accf[oc][1] = __builtin_amdgcn_mfma_f32_16x16x32_bf16(a[kk], bfr[1][kk], accf[oc][1], 0, 0, 0);
            }
        }
        if (m < 8) {
#pragma unroll
            for (int oc = 0; oc < 8; ++oc) {
#pragma unroll
                for (int nt = 0; nt < 2; ++nt) {
                    int node = nodeBase + nt * 16 + c16;
                    if (node >= NN) continue;
                    union { unsigned short s[4]; uint2 v; } pk;
#pragma unroll
                    for (int i = 0; i < 4; ++i) pk.s[i] = f2bf(accf[oc][nt][i]);
                    *reinterpret_cast<uint2*>(h + ((size_t)mi * NN + node) * DD + oc * 16 + grp * 4) = pk.v;
                }
            }
        } else {
#pragma unroll
            for (int oc = 0; oc < 8; ++oc) {
                const float4 bv = *reinterpret_cast<const float4*>(bias + oc * 16 + grp * 4);
#pragma unroll
                for (int nt = 0; nt < 2; ++nt) {
                    int node = nodeBase + nt * 16 + c16;
                    if (node >= NN) continue;
                    float4 o;
                    o.x = accf[oc][nt][0] + bv.x;
                    o.y = accf[oc][nt][1] + bv.y;
                    o.z = accf[oc][nt][2] + bv.z;
                    o.w = accf[oc][nt][3] + bv.w;
                    *reinterpret_cast<float4*>(acc + (size_t)node * DD + oc * 16 + grp * 4) = o;
                }
            }
        }
    }
}

// One wave per dst node: walk segment, count per-relation degrees in-register,
// gather h rows for relations [r0, r0+rcnt), accumulate mean-scaled sum,
// combine with rootio. mode 0: rootio += acc. mode 1: xbout = bf16(relu(rootio+acc)).
// mode 2: rootio = relu(rootio+acc).
__global__ __launch_bounds__(256) void agg_k(const unsigned int* __restrict__ sorted,
                                             const unsigned int* __restrict__ pos,
                                             const unsigned int* __restrict__ degTot,
                                             const unsigned short* __restrict__ h,
                                             float* __restrict__ rootio,
                                             unsigned short* __restrict__ xbout,
                                             int r0, int rcnt, int mode) {
    int node = (int)((blockIdx.x * 256 + threadIdx.x) >> 6);
    if (node >= NN) return;
    const int lane = threadIdx.x & 63;
    const unsigned int len = degTot[node];
    const unsigned int end = pos[node];          // after fill_k: base + len
    const unsigned int beg = end - len;

    // pass 1: per-relation counts, 16-bit fields packed in two u64
    unsigned long long c0 = 0ull, c1 = 0ull;
    for (unsigned int j = beg; j < end; ++j) {
        unsigned int r = sorted[j] >> 20;
        unsigned long long inc = 1ull << (16 * (r & 3));
        if (r < 4) c0 += inc; else c1 += inc;
    }

    // pass 2: gather + mean-scaled accumulate
    float a0 = 0.f, a1 = 0.f;
    for (unsigned int j = beg; j < end; ++j) {
        unsigned int pk = sorted[j];
        unsigned int r  = pk >> 20;
        unsigned int ri = r - (unsigned int)r0;
        if (ri >= (unsigned int)rcnt) continue;
        unsigned int s  = pk & 0xFFFFFu;
        unsigned int cnt = (unsigned int)(((r < 4 ? c0 : c1) >> (16 * (r & 3))) & 0xFFFFu);
        float sc = __builtin_amdgcn_rcpf((float)cnt);
        unsigned int hv = *reinterpret_cast<const unsigned int*>(
            h + ((size_t)ri * NN + s) * DD + lane * 2);
        a0 += bf2f((unsigned short)(hv & 0xffffu)) * sc;
        a1 += bf2f((unsigned short)(hv >> 16)) * sc;
    }

    float* rp = rootio + (size_t)node * DD + lane * 2;
    float2 rv = *reinterpret_cast<float2*>(rp);
    float o0 = rv.x + a0, o1 = rv.y + a1;
    if (mode == 0) {
        *reinterpret_cast<float2*>(rp) = make_float2(o0, o1);
    } else if (mode == 1) {
        o0 = fmaxf(o0, 0.f); o1 = fmaxf(o1, 0.f);
        unsigned int pk2 = ((unsigned int)f2bf(o1) << 16) | (unsigned int)f2bf(o0);
        *reinterpret_cast<unsigned int*>(xbout + (size_t)node * DD + lane * 2) = pk2;
    } else {
        o0 = fmaxf(o0, 0.f); o1 = fmaxf(o1, 0.f);
        *reinterpret_cast<float2*>(rp) = make_float2(o0, o1);
    }
}

extern "C" void kernel_launch(void* const* d_in, const int* in_sizes, int n_in,
                              void* d_out, int out_size, void* d_ws, size_t ws_size,
                              hipStream_t stream) {
    const float* x  = (const float*)d_in[0];
    const int*   ei = (const int*)d_in[1];
    const int*   et = (const int*)d_in[2];
    const float* W1 = (const float*)d_in[3];
    const float* r1 = (const float*)d_in[4];
    const float* b1 = (const float*)d_in[5];
    const float* W2 = (const float*)d_in[6];
    const float* r2 = (const float*)d_in[7];
    const float* b2 = (const float*)d_in[8];
    float* out = (float*)d_out;

    // workspace layout
    char* ws = (char*)d_ws;
    unsigned int*   degTot  = (unsigned int*)ws;                     // 400,000 B
    unsigned int*   counter = degTot + NN;                           // 4 B (pad to 256)
    unsigned int*   pos     = (unsigned int*)(ws + 400256);          // 400,000 B
    unsigned int*   sorted  = (unsigned int*)(ws + 800256);          // 4,000,000 B
    unsigned short* wt1     = (unsigned short*)(ws + 4800256);       // 294,912 B
    unsigned short* wt2     = wt1 + 9 * DD * DD;                     // 294,912 B
    unsigned short* xbuf    = (unsigned short*)(ws + 5390080);       // 25,600,000 B
    unsigned short* h       = xbuf + (size_t)NN * DD;                // C * 25,600,000 B
    const size_t fixedBytes = 5390080 + 25600000;
    const size_t chunkBytes = (size_t)NN * DD * 2;
    if (ws_size < fixedBytes + chunkBytes) return;                   // loud failure
    size_t hcap = (ws_size - fixedBytes) / chunkBytes;
    const int C = hcap >= RR ? RR : (int)hcap;                       // relations per chunk

    const int* srcv = ei;
    const int* dstv = ei + NE;
    const int gemmGrid = (NN + 127) / 128;
    const int aggGrid  = (NN * 64 + 255) / 256;

    hipMemsetAsync(degTot, 0, 400256, stream);                       // degTot + counter
    cvt_x_k<<<(NN * DD / 4 + 255) / 256, 256, 0, stream>>>(x, xbuf, NN * DD / 4);
    cvt_w_k<<<(2 * 9 * DD * DD) / 256, 256, 0, stream>>>(W1, r1, W2, r2, wt1, wt2);
    hist_k<<<(NE + 255) / 256, 256, 0, stream>>>(dstv, degTot);
    offsets_k<<<(NN + 255) / 256, 256, 0, stream>>>(degTot, counter, pos);
    fill_k<<<(NE + 255) / 256, 256, 0, stream>>>(srcv, dstv, et, pos, sorted);

    // ---- layer 1 (root accumulator = d_out; result -> xbuf bf16 with relu) ----
    gemm_k<<<gemmGrid, 256, 0, stream>>>(xbuf, wt1, b1, h, out, 8, 1);
    for (int r0 = 0; r0 < RR; r0 += C) {
        int c = (RR - r0) < C ? (RR - r0) : C;
        gemm_k<<<gemmGrid, 256, 0, stream>>>(xbuf, wt1, b1, h, out, r0, c);
        int mode = (r0 + c == RR) ? 1 : 0;
        agg_k<<<aggGrid, 256, 0, stream>>>(sorted, pos, degTot, h, out, xbuf, r0, c, mode);
    }

    // ---- layer 2 (root accumulator = d_out; final relu in place) ----
    gemm_k<<<gemmGrid, 256, 0, stream>>>(xbuf, wt2, b2, h, out, 8, 1);
    for (int r0 = 0; r0 < RR; r0 += C) {
        int c = (RR - r0) < C ? (RR - r0) : C;
        gemm_k<<<gemmGrid, 256, 0, stream>>>(xbuf, wt2, b2, h, out, r0, c);
        int mode = (r0 + c == RR) ? 2 : 0;
        agg_k<<<aggGrid, 256, 0, stream>>>(sorted, pos, degTot, h, out, xbuf, r0, c, mode);
    }
}